// Round 10
// baseline (151.642 us; speedup 1.0000x reference)
//
#include <hip/hip_runtime.h>
#include <hip/hip_bf16.h>
#include <float.h>

#define N_NODES 100000
#define HID     512
#define NGRAPH  1024
#define BM      48                          // rows per panel
#define NRB     ((N_NODES + BM - 1) / BM)   // 2084 row-panels
#define GRID    256                         // 1 block per CU, persistent sweep

typedef __bf16 bf16_t;
typedef bf16_t bf16x8 __attribute__((ext_vector_type(8)));
typedef float  f32x4  __attribute__((ext_vector_type(4)));

// Branch-free gelu: erf via Abramowitz-Stegun 7.1.26 (|err|<=1.5e-7).
__device__ __forceinline__ float fast_gelu(float x) {
    const float z = __builtin_fabsf(x) * 0.70710678118654752f;
    const float t = __fdividef(1.0f, __builtin_fmaf(0.3275911f, z, 1.0f));
    float p = __builtin_fmaf(1.061405429f, t, -1.453152027f);
    p = __builtin_fmaf(p, t, 1.421413741f);
    p = __builtin_fmaf(p, t, -0.284496736f);
    p = __builtin_fmaf(p, t, 0.254829592f);
    p *= t;
    const float e    = __expf(-z * z);
    const float erfz = __builtin_fmaf(-p, e, 1.0f);
    const float s    = __builtin_copysignf(erfz, x);
    return 0.5f * x * (1.0f + s);
}

// ---- Kernel 0: W1 [K][N] f32 -> tiled bf16 B: unit u=(kt*4+g)*512+col holds
// bf16x8 = W1[kt*32+g*8+e][col], e=0..7 ---------------------------------------
__global__ void __launch_bounds__(256) k_w1t_tiled(const float* __restrict__ w1,
                                                   bf16_t* __restrict__ bt) {
    const int u   = blockIdx.x * 256 + threadIdx.x;   // 0 .. 32767
    const int col = u & 511;
    const int g4  = u >> 9;
    const int k0  = g4 * 8;
    bf16x8 v;
    #pragma unroll
    for (int e = 0; e < 8; ++e)
        v[e] = (bf16_t)w1[(size_t)(k0 + e) * HID + col];
    *reinterpret_cast<bf16x8*>(bt + (size_t)u * 8) = v;
}

// ---- Kernel 1: persistent fused GEMM + gelu + dot(W2) -> gate ---------------
// 256 blocks x 1024 thr (16 waves). Each block sweeps panels rb, rb+256, ...
// A double-buffered in LDS (2x48KB): next panel's loads issue BEFORE the K-loop,
// cvt+ds_write after it (T14). B: direct L2->reg, distance-2 prefetch. 2 barriers
// per panel; K-loop barrier-free. Wave owns 32 cols x 48 rows (acc[3][2]).
__global__ void __launch_bounds__(1024, 4) k_gemm_gate(const float* __restrict__ h,
                                                       const bf16_t* __restrict__ bt,
                                                       const float* __restrict__ b1,
                                                       const float* __restrict__ w2,
                                                       const float* __restrict__ b2,
                                                       float* __restrict__ gate) {
    __shared__ __align__(16) bf16_t As[2][BM * HID];   // 2 x 48KB, swizzled
    __shared__ float gp[16][BM];                       // per-wave row partials

    const int tid  = threadIdx.x;
    const int lane = tid & 63;
    const int wv   = tid >> 6;     // 0..15 : wave owns cols [wv*32, wv*32+32)
    const int l15  = lane & 15;
    const int l4   = lane >> 4;    // 0..3

    // epilogue constants hoisted (fixed per thread)
    float b1v[2], w2v[2];
    #pragma unroll
    for (int nf = 0; nf < 2; ++nf) {
        const int cg = wv * 32 + nf * 16 + l15;
        b1v[nf] = b1[cg];
        w2v[nf] = w2[cg];
    }
    const float b2v = b2[0];

    // B unit for (kt, nf): bbase + kt*16384 + nf*128 (bf16 elements)
    const bf16_t* bbase = bt + ((size_t)l4 * 512 + wv * 32 + l15) * 8;

    // ---- prologue: stage panel rb = bid into As[0] ----
    {
        const int rb = blockIdx.x;
        #pragma unroll
        for (int i = 0; i < 3; ++i) {
            const int idx = i * 1024 + tid;
            const int row = idx >> 6;
            const int cu  = idx & 63;
            const int grow = rb * BM + row;
            f32x4 s0 = f32x4{0.f, 0.f, 0.f, 0.f}, s1 = s0;
            if (grow < N_NODES) {
                const f32x4* p = reinterpret_cast<const f32x4*>(
                    h + (size_t)grow * HID + cu * 8);
                s0 = p[0]; s1 = p[1];
            }
            bf16x8 v;
            #pragma unroll
            for (int j = 0; j < 4; ++j) { v[j] = (bf16_t)s0[j]; v[4 + j] = (bf16_t)s1[j]; }
            *reinterpret_cast<bf16x8*>(
                (char*)&As[0][0] + row * 1024 + ((cu ^ (row & 7)) * 16)) = v;
        }
    }
    __syncthreads();

    int cur = 0;
    for (int rb = blockIdx.x; rb < NRB; rb += GRID) {
        const int  rbn  = rb + GRID;
        const bool have = rbn < NRB;

        // ---- issue-early: next panel's A loads (consumed after the K-loop) ----
        f32x4 st[6];
        if (have) {
            #pragma unroll
            for (int i = 0; i < 3; ++i) {
                const int idx = i * 1024 + tid;
                const int row = idx >> 6;
                const int cu  = idx & 63;
                const int grow = rbn * BM + row;
                f32x4 s0 = f32x4{0.f, 0.f, 0.f, 0.f}, s1 = s0;
                if (grow < N_NODES) {
                    const f32x4* p = reinterpret_cast<const f32x4*>(
                        h + (size_t)grow * HID + cu * 8);
                    s0 = p[0]; s1 = p[1];
                }
                st[2 * i] = s0; st[2 * i + 1] = s1;
            }
        }

        // ---- K loop: 16 tiles of 32, distance-2 B prefetch, barrier-free ----
        const char* abase = (const char*)&As[cur][0] + l15 * 1024;
        f32x4 acc[3][2] = {};
        bf16x8 breg[2][2];
        #pragma unroll
        for (int nf = 0; nf < 2; ++nf)
            breg[0][nf] = *reinterpret_cast<const bf16x8*>(bbase + nf * 128);
        #pragma unroll
        for (int nf = 0; nf < 2; ++nf)
            breg[1][nf] = *reinterpret_cast<const bf16x8*>(bbase + 16384 + nf * 128);
        #pragma unroll 4
        for (int kt = 0; kt < 16; ++kt) {
            const int chunkoff = ((kt * 4 + l4) ^ (l15 & 7)) * 16;
            bf16x8 af[3];
            #pragma unroll
            for (int mf = 0; mf < 3; ++mf)
                af[mf] = *reinterpret_cast<const bf16x8*>(
                    abase + mf * 16384 + chunkoff);
            #pragma unroll
            for (int mf = 0; mf < 3; ++mf)
                #pragma unroll
                for (int nf = 0; nf < 2; ++nf)
                    acc[mf][nf] = __builtin_amdgcn_mfma_f32_16x16x32_bf16(
                        af[mf], breg[kt & 1][nf], acc[mf][nf], 0, 0, 0);
            if (kt < 14) {
                #pragma unroll
                for (int nf = 0; nf < 2; ++nf)
                    breg[kt & 1][nf] = *reinterpret_cast<const bf16x8*>(
                        bbase + (size_t)(kt + 2) * 16384 + nf * 128);
            }
        }

        // ---- write-late: cvt + swizzled ds_write of next panel into other buf -
        if (have) {
            #pragma unroll
            for (int i = 0; i < 3; ++i) {
                const int idx = i * 1024 + tid;
                const int row = idx >> 6;
                const int cu  = idx & 63;
                bf16x8 v;
                #pragma unroll
                for (int j = 0; j < 4; ++j) { v[j] = (bf16_t)st[2*i][j]; v[4+j] = (bf16_t)st[2*i+1][j]; }
                *reinterpret_cast<bf16x8*>(
                    (char*)&As[cur ^ 1][0] + row * 1024 + ((cu ^ (row & 7)) * 16)) = v;
            }
        }

        // ---- epilogue: fast_gelu(acc+b1)*w2, butterfly, cross-wave reduce ----
        float pr[12];
        #pragma unroll
        for (int i = 0; i < 12; ++i) pr[i] = 0.f;
        #pragma unroll
        for (int nf = 0; nf < 2; ++nf) {
            #pragma unroll
            for (int mf = 0; mf < 3; ++mf) {
                #pragma unroll
                for (int rr = 0; rr < 4; ++rr) {
                    const float ge = fast_gelu(acc[mf][nf][rr] + b1v[nf]);
                    pr[mf * 4 + rr] = fmaf(ge, w2v[nf], pr[mf * 4 + rr]);
                }
            }
        }
        #pragma unroll
        for (int i = 0; i < 12; ++i) {
            float v = pr[i];
            v += __shfl_xor(v, 1);
            v += __shfl_xor(v, 2);
            v += __shfl_xor(v, 4);
            v += __shfl_xor(v, 8);
            pr[i] = v;
        }
        __syncthreads();   // previous panel's gp readers done; As[cur^1] writes drained
        if (l15 == 0) {
            #pragma unroll
            for (int mf = 0; mf < 3; ++mf)
                #pragma unroll
                for (int rr = 0; rr < 4; ++rr)
                    gp[wv][mf * 16 + l4 * 4 + rr] = pr[mf * 4 + rr];
        }
        __syncthreads();
        if (tid < BM) {
            const int grow = rb * BM + tid;
            if (grow < N_NODES) {
                float s = b2v;
                #pragma unroll
                for (int w = 0; w < 16; ++w) s += gp[w][tid];
                gate[grow] = s;
            }
        }
        cur ^= 1;
    }
}

// ---- Kernel 2: segment softmax + weighted pool ------------------------------
__global__ void __launch_bounds__(256) k_pool(const float* __restrict__ h,
                                              const int* __restrict__ bv,
                                              const float* __restrict__ gate,
                                              float* __restrict__ out) {
    const int g   = blockIdx.x;
    const int tid = threadIdx.x;
    __shared__ int   s_bounds[2];
    __shared__ float s_red[4];
    __shared__ float s_alpha[256];

    if (tid == 0) {
        int lo = 0, hi = N_NODES;
        while (lo < hi) { int mid = (lo + hi) >> 1; if (bv[mid] < g) lo = mid + 1; else hi = mid; }
        s_bounds[0] = lo;
        int lo2 = lo, hi2 = N_NODES;
        while (lo2 < hi2) { int mid = (lo2 + hi2) >> 1; if (bv[mid] < g + 1) lo2 = mid + 1; else hi2 = mid; }
        s_bounds[1] = lo2;
    }
    __syncthreads();
    const int start = s_bounds[0], end = s_bounds[1];

    float2 acc = make_float2(0.f, 0.f);
    if (start < end) {
        const int lane = tid & 63, wv = tid >> 6;
        float lm = -FLT_MAX;
        for (int i = start + tid; i < end; i += 256) lm = fmaxf(lm, gate[i]);
        #pragma unroll
        for (int o = 32; o; o >>= 1) lm = fmaxf(lm, __shfl_xor(lm, o));
        if (lane == 0) s_red[wv] = lm;
        __syncthreads();
        const float m = fmaxf(fmaxf(s_red[0], s_red[1]), fmaxf(s_red[2], s_red[3]));
        __syncthreads();
        float ls = 0.f;
        for (int i = start + tid; i < end; i += 256) ls += expf(gate[i] - m);
        #pragma unroll
        for (int o = 32; o; o >>= 1) ls += __shfl_xor(ls, o);
        if (lane == 0) s_red[wv] = ls;
        __syncthreads();
        const float inv = 1.f / (s_red[0] + s_red[1] + s_red[2] + s_red[3]);
        const float* hcol = h + tid * 2;
        for (int base = start; base < end; base += 256) {
            const int j = base + tid;
            const float av = (j < end) ? expf(gate[j] - m) * inv : 0.f;
            __syncthreads();
            s_alpha[tid] = av;
            __syncthreads();
            const int cnt = min(256, end - base);
            for (int jj = 0; jj < cnt; ++jj) {
                const float a = s_alpha[jj];
                const float2 hv = *reinterpret_cast<const float2*>(
                    hcol + (size_t)(base + jj) * HID);
                acc.x = fmaf(a, hv.x, acc.x);
                acc.y = fmaf(a, hv.y, acc.y);
            }
        }
    }
    *reinterpret_cast<float2*>(out + (size_t)g * HID + tid * 2) = acc;
}

// ---- launcher ---------------------------------------------------------------
extern "C" void kernel_launch(void* const* d_in, const int* in_sizes, int n_in,
                              void* d_out, int out_size, void* d_ws, size_t ws_size,
                              hipStream_t stream) {
    const float* h  = (const float*)d_in[0];
    const int*   bv = (const int*)d_in[1];
    const float* W1 = (const float*)d_in[2];
    const float* b1 = (const float*)d_in[3];
    const float* W2 = (const float*)d_in[4];
    const float* b2 = (const float*)d_in[5];
    float* out = (float*)d_out;

    char* ws = (char*)d_ws;
    bf16_t* bt   = (bf16_t*)ws;                    // tiled B: 512*512*2 = 524288 B
    float*  gate = (float*)(ws + 524288);          // 100000*4 B

    k_w1t_tiled<<<dim3(128), dim3(256), 0, stream>>>(W1, bt);
    k_gemm_gate<<<dim3(GRID), dim3(1024), 0, stream>>>(h, bt, b1, W2, b2, gate);
    k_pool<<<dim3(NGRAPH), dim3(256), 0, stream>>>(h, bv, gate, out);
}

// Round 11
// 140.576 us; speedup vs baseline: 1.0787x; 1.0787x over previous
//
#include <hip/hip_runtime.h>
#include <hip/hip_bf16.h>
#include <float.h>

#define N_NODES 100000
#define HID     512
#define NGRAPH  1024
#define BM      48            // rows per block
#define NBLK    ((N_NODES + BM - 1) / BM)   // 2084

typedef __bf16 bf16_t;
typedef bf16_t bf16x8 __attribute__((ext_vector_type(8)));
typedef float  f32x4  __attribute__((ext_vector_type(4)));

// Branch-free gelu: erf via Abramowitz-Stegun 7.1.26 (|err|<=1.5e-7).
__device__ __forceinline__ float fast_gelu(float x) {
    const float z = __builtin_fabsf(x) * 0.70710678118654752f;
    const float t = __fdividef(1.0f, __builtin_fmaf(0.3275911f, z, 1.0f));
    float p = __builtin_fmaf(1.061405429f, t, -1.453152027f);
    p = __builtin_fmaf(p, t, 1.421413741f);
    p = __builtin_fmaf(p, t, -0.284496736f);
    p = __builtin_fmaf(p, t, 0.254829592f);
    p *= t;
    const float e    = __expf(-z * z);
    const float erfz = __builtin_fmaf(-p, e, 1.0f);
    const float s    = __builtin_copysignf(erfz, x);
    return 0.5f * x * (1.0f + s);
}

// ---- Kernel 0: W1 [K][N] f32 -> tiled bf16 B: unit u=(kt*4+g)*512+col holds
// bf16x8 = W1[kt*32+g*8+e][col], e=0..7 ---------------------------------------
__global__ void __launch_bounds__(256) k_w1t_tiled(const float* __restrict__ w1,
                                                   bf16_t* __restrict__ bt) {
    const int u   = blockIdx.x * 256 + threadIdx.x;   // 0 .. 32767
    const int col = u & 511;
    const int g4  = u >> 9;
    const int k0  = g4 * 8;
    bf16x8 v;
    #pragma unroll
    for (int e = 0; e < 8; ++e)
        v[e] = (bf16_t)w1[(size_t)(k0 + e) * HID + col];
    *reinterpret_cast<bf16x8*>(bt + (size_t)u * 8) = v;
}

// ---- Kernel 1: fused GEMM + gelu + dot(W2) -> gate --------------------------
// Round-7 geometry (8 waves, 48x64 wave tile, acc[3][4], MFMA:ds_read = 4:1,
// 51KB LDS -> 2 blocks/CU) + WAVE-STAGGERED K-loop: wave wv of block bid starts
// at tile (2*wv ^ bid)&15 and wraps. Decorrelates the per-pipe demand bursts
// (LDS / matrix / L2) that phase-locked waves produce. Accumulation order change
// only perturbs fp32 rounding. No K-loop barriers; single-buffered B.
__global__ void __launch_bounds__(512, 2) k_gemm_gate(const float* __restrict__ h,
                                                      const bf16_t* __restrict__ bt,
                                                      const float* __restrict__ b1,
                                                      const float* __restrict__ w2,
                                                      const float* __restrict__ b2,
                                                      float* __restrict__ gate) {
    __shared__ __align__(16) bf16_t As[BM * HID];   // 48KB: [48 rows][512 k], swizzled
    __shared__ float gp[8][BM];                     // per-wave row partials

    const int tid  = threadIdx.x;
    const int lane = tid & 63;
    const int wv   = tid >> 6;     // 0..7 : wave owns cols [wv*64, wv*64+64)
    const int l15  = lane & 15;
    const int l4   = lane >> 4;    // 0..3

    const int brow = blockIdx.x * BM;

    // ================= stage A: 48 rows x 2KB, coalesced =======================
    #pragma unroll
    for (int i = 0; i < 6; ++i) {
        const int idx = i * 512 + tid;
        const int row = idx >> 6;
        const int cu  = idx & 63;
        const int grow = brow + row;
        f32x4 s0 = f32x4{0.f, 0.f, 0.f, 0.f}, s1 = s0;
        if (grow < N_NODES) {
            const f32x4* p = reinterpret_cast<const f32x4*>(
                h + (size_t)grow * HID + cu * 8);
            s0 = p[0];
            s1 = p[1];
        }
        bf16x8 v;
        #pragma unroll
        for (int j = 0; j < 4; ++j) { v[j] = (bf16_t)s0[j]; v[4 + j] = (bf16_t)s1[j]; }
        *reinterpret_cast<bf16x8*>(
            (char*)As + row * 1024 + ((cu ^ (row & 7)) * 16)) = v;
    }
    __syncthreads();   // the ONLY barrier before the epilogue

    // ================= K loop: 16 tiles of 32, wave-staggered, barrier-free ====
    // B unit for (kt, nf): bbase + kt*16384 + nf*128 (bf16 elements)
    const bf16_t* bbase = bt + ((size_t)l4 * 512 + wv * 64 + l15) * 8;
    const char*   abase = (const char*)As + l15 * 1024;   // + mf*16384 + chunkoff
    const int     sh    = ((wv << 1) ^ blockIdx.x) & 15;  // per-wave phase offset
    f32x4 acc[3][4] = {};
    #pragma unroll
    for (int t = 0; t < 16; ++t) {
        const int kt = (t + sh) & 15;
        bf16x8 bfr[4];
        #pragma unroll
        for (int nf = 0; nf < 4; ++nf)
            bfr[nf] = *reinterpret_cast<const bf16x8*>(
                bbase + (size_t)kt * 16384 + nf * 128);
        const int chunkoff = ((kt * 4 + l4) ^ (l15 & 7)) * 16;
        bf16x8 af[3];
        #pragma unroll
        for (int mf = 0; mf < 3; ++mf)
            af[mf] = *reinterpret_cast<const bf16x8*>(abase + mf * 16384 + chunkoff);
        #pragma unroll
        for (int mf = 0; mf < 3; ++mf)
            #pragma unroll
            for (int nf = 0; nf < 4; ++nf)
                acc[mf][nf] = __builtin_amdgcn_mfma_f32_16x16x32_bf16(
                    af[mf], bfr[nf], acc[mf][nf], 0, 0, 0);
    }

    // ================= epilogue: fast_gelu(acc+b1)*w2, reduce 512 cols =========
    float pr[12];
    #pragma unroll
    for (int i = 0; i < 12; ++i) pr[i] = 0.f;
    #pragma unroll
    for (int nf = 0; nf < 4; ++nf) {
        const int cg    = wv * 64 + nf * 16 + l15;
        const float b1v = b1[cg];
        const float w2v = w2[cg];
        #pragma unroll
        for (int mf = 0; mf < 3; ++mf) {
            #pragma unroll
            for (int rr = 0; rr < 4; ++rr) {
                const float ge = fast_gelu(acc[mf][nf][rr] + b1v);
                pr[mf * 4 + rr] = fmaf(ge, w2v, pr[mf * 4 + rr]);
            }
        }
    }
    #pragma unroll
    for (int i = 0; i < 12; ++i) {
        float v = pr[i];
        v += __shfl_xor(v, 1);
        v += __shfl_xor(v, 2);
        v += __shfl_xor(v, 4);
        v += __shfl_xor(v, 8);
        pr[i] = v;
    }
    if (l15 == 0) {
        #pragma unroll
        for (int mf = 0; mf < 3; ++mf)
            #pragma unroll
            for (int rr = 0; rr < 4; ++rr)
                gp[wv][mf * 16 + l4 * 4 + rr] = pr[mf * 4 + rr];
    }
    __syncthreads();
    if (tid < BM) {
        const int grow = brow + tid;
        if (grow < N_NODES) {
            float s = b2[0];
            #pragma unroll
            for (int w = 0; w < 8; ++w) s += gp[w][tid];
            gate[grow] = s;
        }
    }
}

// ---- Kernel 2: segment softmax + weighted pool ------------------------------
__global__ void __launch_bounds__(256) k_pool(const float* __restrict__ h,
                                              const int* __restrict__ bv,
                                              const float* __restrict__ gate,
                                              float* __restrict__ out) {
    const int g   = blockIdx.x;
    const int tid = threadIdx.x;
    __shared__ int   s_bounds[2];
    __shared__ float s_red[4];
    __shared__ float s_alpha[256];

    if (tid == 0) {
        int lo = 0, hi = N_NODES;
        while (lo < hi) { int mid = (lo + hi) >> 1; if (bv[mid] < g) lo = mid + 1; else hi = mid; }
        s_bounds[0] = lo;
        int lo2 = lo, hi2 = N_NODES;
        while (lo2 < hi2) { int mid = (lo2 + hi2) >> 1; if (bv[mid] < g + 1) lo2 = mid + 1; else hi2 = mid; }
        s_bounds[1] = lo2;
    }
    __syncthreads();
    const int start = s_bounds[0], end = s_bounds[1];

    float2 acc = make_float2(0.f, 0.f);
    if (start < end) {
        const int lane = tid & 63, wv = tid >> 6;
        float lm = -FLT_MAX;
        for (int i = start + tid; i < end; i += 256) lm = fmaxf(lm, gate[i]);
        #pragma unroll
        for (int o = 32; o; o >>= 1) lm = fmaxf(lm, __shfl_xor(lm, o));
        if (lane == 0) s_red[wv] = lm;
        __syncthreads();
        const float m = fmaxf(fmaxf(s_red[0], s_red[1]), fmaxf(s_red[2], s_red[3]));
        __syncthreads();
        float ls = 0.f;
        for (int i = start + tid; i < end; i += 256) ls += expf(gate[i] - m);
        #pragma unroll
        for (int o = 32; o; o >>= 1) ls += __shfl_xor(ls, o);
        if (lane == 0) s_red[wv] = ls;
        __syncthreads();
        const float inv = 1.f / (s_red[0] + s_red[1] + s_red[2] + s_red[3]);
        const float* hcol = h + tid * 2;
        for (int base = start; base < end; base += 256) {
            const int j = base + tid;
            const float av = (j < end) ? expf(gate[j] - m) * inv : 0.f;
            __syncthreads();
            s_alpha[tid] = av;
            __syncthreads();
            const int cnt = min(256, end - base);
            for (int jj = 0; jj < cnt; ++jj) {
                const float a = s_alpha[jj];
                const float2 hv = *reinterpret_cast<const float2*>(
                    hcol + (size_t)(base + jj) * HID);
                acc.x = fmaf(a, hv.x, acc.x);
                acc.y = fmaf(a, hv.y, acc.y);
            }
        }
    }
    *reinterpret_cast<float2*>(out + (size_t)g * HID + tid * 2) = acc;
}

// ---- launcher ---------------------------------------------------------------
extern "C" void kernel_launch(void* const* d_in, const int* in_sizes, int n_in,
                              void* d_out, int out_size, void* d_ws, size_t ws_size,
                              hipStream_t stream) {
    const float* h  = (const float*)d_in[0];
    const int*   bv = (const int*)d_in[1];
    const float* W1 = (const float*)d_in[2];
    const float* b1 = (const float*)d_in[3];
    const float* W2 = (const float*)d_in[4];
    const float* b2 = (const float*)d_in[5];
    float* out = (float*)d_out;

    char* ws = (char*)d_ws;
    bf16_t* bt   = (bf16_t*)ws;                    // tiled B: 512*512*2 = 524288 B
    float*  gate = (float*)(ws + 524288);          // 100000*4 B

    k_w1t_tiled<<<dim3(128), dim3(256), 0, stream>>>(W1, bt);
    k_gemm_gate<<<dim3(NBLK), dim3(512), 0, stream>>>(h, bt, b1, W2, b2, gate);
    k_pool<<<dim3(NGRAPH), dim3(256), 0, stream>>>(h, bv, gate, out);
}